// Round 10
// baseline (1612.196 us; speedup 1.0000x reference)
//
#include <hip/hip_runtime.h>

// NeuralODE: B=1024, D=64, F=8, H=256, 196 substeps x 6 dopri5 stages.
// R10: flag-pipeline MFMA. R9 showed 4 block-wide barriers/stage cost ~2300
// of 3255 cyc/stage (all pipes <15% busy). Replace __syncthreads with LDS
// monotonic counters (release ds_add / acquire poll + s_sleep backoff):
//   zc: z ready (5 producers: 4 state waves x-part + wave4 u-part)
//   hc: h ready (8 producers: waves 4-11, 2 N-tiles each)
//   uc: ush ready (6 producers: waves 4-9, NEXT step prefetched off-path)
// z/h double-buffered by stage parity (s&1), ush by step parity; WAR safety
// follows transitively from the flag chain (writer of buf(gs) is provably
// behind all readers of buf(gs-2)).
// Waves 0-3: state + full-K GEMM2 (16 MFMAs, 8 depth-2 accum chains) -> the
// red[] LDS reduce round-trip and its barrier are deleted.
// Waves 4-11: GEMM1 (2 tiles: 6 b128-equiv A-reads, 12 MFMAs, tanh, store).
// ONE shared wfrag[16] register array per thread (R5/R6 lesson: static live
// set must fit the budget summed over arrays, not per duty path).
// 64 blocks x 768 threads (12 waves, 3/SIMD, waves_per_eu(3,3): 170-reg
// budget; worst path ~148). A-frag LDS planes [k>>3][m][k&7], stride 144
// halves. MFMA layouts HW-verified (R7-R9 pass).

typedef _Float16 half8 __attribute__((ext_vector_type(8)));
typedef float f32x4 __attribute__((ext_vector_type(4)));

#define MFMA16(a, b, c) __builtin_amdgcn_mfma_f32_16x16x32_f16((a), (b), (c), 0, 0, 0)

__device__ __forceinline__ float fast_tanh(float x) {
    float e = __expf(2.0f * x);
    return 1.0f - 2.0f / (e + 1.0f);   // saturates correctly, ~1e-6 abs err
}

__device__ __forceinline__ void wg_poll(int* c, int tgt) {
    while (__hip_atomic_load(c, __ATOMIC_ACQUIRE, __HIP_MEMORY_SCOPE_WORKGROUP) < tgt)
        __builtin_amdgcn_s_sleep(1);
}
__device__ __forceinline__ void wg_post(int* c, int lane) {
    if (lane == 0)
        (void)__hip_atomic_fetch_add(c, 1, __ATOMIC_RELEASE, __HIP_MEMORY_SCOPE_WORKGROUP);
}

__global__ __attribute__((amdgpu_waves_per_eu(3, 3))) __launch_bounds__(768)
void node_kernel(const float* __restrict__ x0,
                 const float* __restrict__ t_eval,
                 const float* __restrict__ t_u,
                 const float* __restrict__ u_batch,
                 const float* __restrict__ W1,
                 const float* __restrict__ b1,
                 const float* __restrict__ W2,
                 const float* __restrict__ b2,
                 float* __restrict__ out)
{
    __shared__ __align__(16) _Float16 zA[2][1728];     // 12 planes x 144
    __shared__ __align__(16) _Float16 hA[2][4608];     // 32 planes x 144
    __shared__ __align__(16) float ush[2][6][16][8];   // step-parity u
    __shared__ int zc, hc, uc;

    const int tid = threadIdx.x;
    const int wv  = tid >> 6;        // 0..11
    const int l   = tid & 63;
    const int lm  = l & 15;
    const int lq  = l >> 4;
    const int blk = blockIdx.x;
    const bool is_st = (wv < 4);

    if (tid == 0) { zc = 0; hc = 0; uc = 0; }
    // zero both z buffers (covers the K-pad planes 9..11 permanently)
    for (int i = tid; i < 1728; i += 768) ((uint32_t*)zA)[i] = 0u;

    // --- ONE shared frag array; contents duty-dependent (R6 lesson) ---
    half8 wfrag[16];
    float bias0 = 0.f, bias1 = 0.f;
    const int n2 = (wv & 3) * 16 + lm;     // state: output col; also reused below
    if (is_st) {
        // GEMM2 B-frags, 2-term split, full K=256: wfrag[2c]=hi, [2c+1]=lo
#pragma unroll
        for (int c = 0; c < 8; ++c) {
            half8 bh, bl;
#pragma unroll
            for (int j = 0; j < 8; ++j) {
                const int k = c * 32 + lq * 8 + j;
                const float v = W2[k * 64 + n2];
                const _Float16 hi = (_Float16)v;
                bh[j] = hi;
                bl[j] = (_Float16)(v - (float)hi);
            }
            wfrag[c * 2] = bh;
            wfrag[c * 2 + 1] = bl;
        }
        bias0 = b2[n2];
    } else {
        // GEMM1 B-frags for tiles t=(wv-4)*2, +1: wfrag[t2*6 + 2c{,+1}]
#pragma unroll
        for (int t2 = 0; t2 < 2; ++t2) {
            const int n1 = ((wv - 4) * 2 + t2) * 16 + lm;
#pragma unroll
            for (int c = 0; c < 3; ++c) {
                half8 bh, bl;
#pragma unroll
                for (int j = 0; j < 8; ++j) {
                    const int k = c * 32 + lq * 8 + j;
                    const float v = (k < 72) ? W1[k * 256 + n1] : 0.0f;
                    const _Float16 hi = (_Float16)v;
                    bh[j] = hi;
                    bl[j] = (_Float16)(v - (float)hi);
                }
                wfrag[t2 * 6 + c * 2] = bh;
                wfrag[t2 * 6 + c * 2 + 1] = bl;
            }
        }
        bias0 = b1[((wv - 4) * 2) * 16 + lm];
        bias1 = b1[((wv - 4) * 2 + 1) * 16 + lm];
    }

    float xr[4];
    float kfr[5][4];
    if (is_st) {
#pragma unroll
        for (int r = 0; r < 4; ++r) {
            const int gr = blk * 16 + lq * 4 + r;
            xr[r] = x0[gr * 64 + n2];
            out[gr * 3200 + n2] = xr[r];        // t_eval[0]
        }
    }

    // --- u(step 0) produced before the loop (waves 4..9, one stage each) ---
    if (wv >= 4 && wv <= 9) {
        const int s = wv - 4;
        const float te0 = t_eval[0];
        const float dtc = t_eval[1] - te0;
        const float dtq = dtc * 0.25f;
        float cs;
        switch (s) {
            case 0: cs = 0.0f; break;
            case 1: cs = 1.0f/5.0f; break;
            case 2: cs = 3.0f/10.0f; break;
            case 3: cs = 4.0f/5.0f; break;
            case 4: cs = 8.0f/9.0f; break;
            default: cs = 1.0f; break;
        }
        const float tsv = te0 + dtq * cs;
        int iu = (int)(tsv * 127.0f);
        iu = iu < 0 ? 0 : (iu > 126 ? 126 : iu);
        const float ta = t_u[iu], tb = t_u[iu + 1];
        const float wt = (tsv - ta) / (tb - ta);
#pragma unroll
        for (int h2 = 0; h2 < 2; ++h2) {
            const int rem = h2 * 64 + l;
            const int mr = rem >> 3, f = rem & 7;
            const float* ub = &u_batch[(blk * 16 + mr) * 1024 + iu * 8 + f];
            ush[0][s][mr][f] = fmaf(wt, ub[8] - ub[0], ub[0]);
        }
        wg_post(&uc, l);
    }
    __syncthreads();   // one real barrier: init visible

#pragma unroll 1
    for (int step = 0; step < 196; ++step) {
        const int n = step >> 2, m = step & 3;
        const float te0 = t_eval[n];
        const float dtc = t_eval[n + 1] - te0;
        const float dt  = dtc * 0.25f;

        // --- prefetch u(step+1) off-path (waves 4..9) ---
        if (wv >= 4 && wv <= 9 && step + 1 < 196) {
            const int q = step + 1;
            const int qn = q >> 2, qm = q & 3;
            const int s = wv - 4;
            const float qte0 = t_eval[qn];
            const float qdtc = t_eval[qn + 1] - qte0;
            const float qt   = qte0 + qdtc * (0.25f * (float)qm);
            const float qdt  = qdtc * 0.25f;
            float cs;
            switch (s) {
                case 0: cs = 0.0f; break;
                case 1: cs = 1.0f/5.0f; break;
                case 2: cs = 3.0f/10.0f; break;
                case 3: cs = 4.0f/5.0f; break;
                case 4: cs = 8.0f/9.0f; break;
                default: cs = 1.0f; break;
            }
            const float tsv = qt + qdt * cs;
            int iu = (int)(tsv * 127.0f);
            iu = iu < 0 ? 0 : (iu > 126 ? 126 : iu);
            const float ta = t_u[iu], tb = t_u[iu + 1];
            const float wt = (tsv - ta) / (tb - ta);
#pragma unroll
            for (int h2 = 0; h2 < 2; ++h2) {
                const int rem = h2 * 64 + l;
                const int mr = rem >> 3, f = rem & 7;
                const float* ub = &u_batch[(blk * 16 + mr) * 1024 + iu * 8 + f];
                ush[q & 1][s][mr][f] = fmaf(wt, ub[8] - ub[0], ub[0]);
            }
            wg_post(&uc, l);
        }

#pragma unroll
        for (int s = 0; s < 6; ++s) {
            const int gs = step * 6 + s;        // folds to step*6 + const
            _Float16* zp = zA[s & 1];           // step*6 even -> parity = s&1
            _Float16* hp = hA[s & 1];

            if (is_st) {
                // --- z x-part (Butcher combo, const-indexed kfr) ---
#pragma unroll
                for (int r = 0; r < 4; ++r) {
                    float v;
                    if (s == 0)      v = xr[r];
                    else if (s == 1) v = fmaf(dt, kfr[0][r] * (1.0f/5.0f), xr[r]);
                    else if (s == 2) v = fmaf(dt, fmaf(3.0f/40.0f, kfr[0][r], (9.0f/40.0f)*kfr[1][r]), xr[r]);
                    else if (s == 3) v = fmaf(dt, (44.0f/45.0f)*kfr[0][r] + (-56.0f/15.0f)*kfr[1][r]
                                                 + (32.0f/9.0f)*kfr[2][r], xr[r]);
                    else if (s == 4) v = fmaf(dt, (19372.0f/6561.0f)*kfr[0][r] + (-25360.0f/2187.0f)*kfr[1][r]
                                                 + (64448.0f/6561.0f)*kfr[2][r] + (-212.0f/729.0f)*kfr[3][r], xr[r]);
                    else             v = fmaf(dt, (9017.0f/3168.0f)*kfr[0][r] + (-355.0f/33.0f)*kfr[1][r]
                                                 + (46732.0f/5247.0f)*kfr[2][r] + (49.0f/176.0f)*kfr[3][r]
                                                 + (-5103.0f/18656.0f)*kfr[4][r], xr[r]);
                    zp[(n2 >> 3) * 144 + (lq * 4 + r) * 8 + (n2 & 7)] = (_Float16)v;
                }
                wg_post(&zc, l);

                // --- GEMM2: poll h, full K=256, 8 depth-2 accum chains ---
                wg_poll(&hc, 8 * (gs + 1));
                f32x4 aH[4], aL[4];
#pragma unroll
                for (int i = 0; i < 4; ++i) { aH[i] = (f32x4){0.f,0.f,0.f,0.f}; aL[i] = (f32x4){0.f,0.f,0.f,0.f}; }
#pragma unroll
                for (int c = 0; c < 8; ++c) {
                    const half8 ah = *(const half8*)&hp[(c * 4 + lq) * 144 + lm * 8];
                    aH[c & 3] = MFMA16(ah, wfrag[c * 2], aH[c & 3]);
                    aL[c & 3] = MFMA16(ah, wfrag[c * 2 + 1], aL[c & 3]);
                }
                const f32x4 sum = ((aH[0] + aH[1]) + (aH[2] + aH[3]))
                                + ((aL[0] + aL[1]) + (aL[2] + aL[3]));
                if (s < 5) {
#pragma unroll
                    for (int r = 0; r < 4; ++r) kfr[s][r] = sum[r] + bias0;
                } else {
#pragma unroll
                    for (int r = 0; r < 4; ++r) {
                        const float k6 = sum[r] + bias0;
                        xr[r] = fmaf(dt, (35.0f/384.0f)*kfr[0][r] + (500.0f/1113.0f)*kfr[2][r]
                                        + (125.0f/192.0f)*kfr[3][r] + (-2187.0f/6784.0f)*kfr[4][r]
                                        + (11.0f/84.0f)*k6, xr[r]);
                    }
                    if (m == 3) {
#pragma unroll
                        for (int r = 0; r < 4; ++r)
                            out[(blk * 16 + lq * 4 + r) * 3200 + (n + 1) * 64 + n2] = xr[r];
                    }
                }
            } else {
                // --- wave 4: z u-part (dword-packed) ---
                if (wv == 4) {
                    if (s == 0) wg_poll(&uc, 6 * (step + 1));
                    const int mm = l >> 2, jj = (l & 3) * 2;
                    const _Float16 h0 = (_Float16)ush[step & 1][s][mm][jj];
                    const _Float16 h1 = (_Float16)ush[step & 1][s][mm][jj + 1];
                    const uint32_t pk = (uint32_t)*(const uint16_t*)&h0
                                      | ((uint32_t)*(const uint16_t*)&h1 << 16);
                    *(uint32_t*)&zp[8 * 144 + mm * 8 + jj] = pk;
                    wg_post(&zc, l);
                }
                // --- GEMM1: poll z, 2 N-tiles, 2-term split ---
                wg_poll(&zc, 5 * (gs + 1));
                const half8 az0 = *(const half8*)&zp[(0 * 4 + lq) * 144 + lm * 8];
                const half8 az1 = *(const half8*)&zp[(1 * 4 + lq) * 144 + lm * 8];
                const half8 az2 = *(const half8*)&zp[(2 * 4 + lq) * 144 + lm * 8];
#pragma unroll
                for (int t2 = 0; t2 < 2; ++t2) {
                    f32x4 aHH = {0.f, 0.f, 0.f, 0.f};
                    f32x4 aHL = {0.f, 0.f, 0.f, 0.f};
                    aHH = MFMA16(az0, wfrag[t2 * 6 + 0], aHH);
                    aHL = MFMA16(az0, wfrag[t2 * 6 + 1], aHL);
                    aHH = MFMA16(az1, wfrag[t2 * 6 + 2], aHH);
                    aHL = MFMA16(az1, wfrag[t2 * 6 + 3], aHL);
                    aHH = MFMA16(az2, wfrag[t2 * 6 + 4], aHH);
                    aHL = MFMA16(az2, wfrag[t2 * 6 + 5], aHL);
                    const float bb = t2 ? bias1 : bias0;
                    const int tt = (wv - 4) * 2 + t2;
                    const int kqb = tt * 2 + (lm >> 3);
#pragma unroll
                    for (int r = 0; r < 4; ++r) {
                        const float hv = fast_tanh(aHH[r] + aHL[r] + bb);
                        hp[kqb * 144 + (lq * 4 + r) * 8 + (lm & 7)] = (_Float16)hv;
                    }
                }
                wg_post(&hc, l);
            }
        }
    }
}

extern "C" void kernel_launch(void* const* d_in, const int* in_sizes, int n_in,
                              void* d_out, int out_size, void* d_ws, size_t ws_size,
                              hipStream_t stream) {
    const float* x0      = (const float*)d_in[0];
    const float* t_eval  = (const float*)d_in[1];
    const float* t_u     = (const float*)d_in[2];
    const float* u_batch = (const float*)d_in[3];
    const float* W1      = (const float*)d_in[4];
    const float* b1      = (const float*)d_in[5];
    const float* W2      = (const float*)d_in[6];
    const float* b2      = (const float*)d_in[7];
    float* out = (float*)d_out;

    node_kernel<<<dim3(64), dim3(768), 0, stream>>>(
        x0, t_eval, t_u, u_batch, W1, b1, W2, b2, out);
}